// Round 6
// baseline (165.077 us; speedup 1.0000x reference)
//
#include <hip/hip_runtime.h>
#include <hip/hip_bf16.h>

#define EPSV 1e-5f

typedef short bf16x8 __attribute__((ext_vector_type(8)));
typedef short bf16x4 __attribute__((ext_vector_type(4)));
typedef float f32x4  __attribute__((ext_vector_type(4)));

__device__ __forceinline__ short f2bf(float f){
  unsigned u = __float_as_uint(f);
  u += 0x7fff + ((u >> 16) & 1);     // RNE
  return (short)(u >> 16);
}
__device__ __forceinline__ int pk2(float a, float b){
  __hip_bfloat162 h = __float22bfloat162_rn(float2{a, b});
  return *reinterpret_cast<int*>(&h);
}

// ---------------------------------------------------------------------------
// Kernel A: Wb[b][j][co][ci] = bf16(conv_w[co][ci][j] + scale * (B@A)[b][co][ci*5+j])
// ---------------------------------------------------------------------------
__global__ void build_weights(const float* __restrict__ A_flat,
                              const float* __restrict__ B_flat,
                              const float* __restrict__ conv_w,
                              const float* __restrict__ scale_p,
                              short* __restrict__ Wb){
  int idx = blockIdx.x * 256 + threadIdx.x;   // ((b*5+j)*128 + co)*64 + ci
  int ci = idx & 63;
  int co = (idx >> 6) & 127;
  int bj = idx >> 13;          // 0..159
  int b  = bj / 5;
  int j  = bj - 5 * b;
  int m  = ci * 5 + j;
  const float* Bp = B_flat + (b * 128 + co) * 8;
  const float* Ap = A_flat + b * 8 * 320 + m;
  float d = 0.f;
#pragma unroll
  for (int r = 0; r < 8; ++r) d = fmaf(Bp[r], Ap[r * 320], d);
  float w = conv_w[co * 320 + m] + scale_p[0] * d;
  Wb[idx] = f2bf(w);
}

// ---------------------------------------------------------------------------
// Kernel T: xT[s][col+2][ci] = bf16(x[s][ci][col]); rows 0,1,2050,2051 zero.
// Block = (sample, col-quarter of 512). LDS transpose, pitch 66 shorts.
// ---------------------------------------------------------------------------
#define XP 66                      // shorts per col row (64 ci + 2 pad)
__global__ __launch_bounds__(256, 8)
void xpose(const float* __restrict__ x, short* __restrict__ xT){
  __shared__ short xl[512 * XP];   // 67584 B
  const int bid  = blockIdx.x;
  const int s    = bid >> 2;
  const int q    = bid & 3;        // col quarter
  const int tid  = threadIdx.x;
  const int lane = tid & 63;
  const int wid  = tid >> 6;       // 0..3

  // stage: wave w covers ci rows [w*16, w*16+16), 4 rows at a time
  const float* xs = x + (size_t)s * 64 * 2048 + q * 512;
#pragma unroll
  for (int grp = 0; grp < 4; ++grp) {
    const int ci0 = wid * 16 + grp * 4;
    const float* xr = xs + (size_t)ci0 * 2048;
#pragma unroll
    for (int pass = 0; pass < 2; ++pass) {
      int c0 = pass * 256 + lane * 4;
      float4 v0 = *(const float4*)(xr + c0);
      float4 v1 = *(const float4*)(xr + c0 + 2048);
      float4 v2 = *(const float4*)(xr + c0 + 4096);
      float4 v3 = *(const float4*)(xr + c0 + 6144);
      const float a0[4] = {v0.x, v0.y, v0.z, v0.w};
      const float a1[4] = {v1.x, v1.y, v1.z, v1.w};
      const float a2[4] = {v2.x, v2.y, v2.z, v2.w};
      const float a3[4] = {v3.x, v3.y, v3.z, v3.w};
#pragma unroll
      for (int k = 0; k < 4; ++k) {
        int base = (c0 + k) * XP + ci0;          // 4-B aligned (ci0 mult of 4)
        *(int*)&xl[base]     = pk2(a0[k], a1[k]);
        *(int*)&xl[base + 2] = pk2(a2[k], a3[k]);
      }
    }
  }
  __syncthreads();

  // drain: wave w covers cols [w*128, w*128+128); lane = 4 cols x 16 ci4
  short* dst = xT + ((size_t)s * 2052 + 2 + q * 512) * 64;
  const int ci4 = lane & 15;
#pragma unroll
  for (int it = 0; it < 32; ++it) {
    int col = wid * 128 + it * 4 + (lane >> 4);
    int base = col * XP + ci4 * 4;
    int r0 = *(const int*)&xl[base];
    int r1 = *(const int*)&xl[base + 2];
    *(int2*)(dst + (size_t)col * 64 + ci4 * 4) = int2{r0, r1};
  }
  // zero pad rows
  if (q == 0 && tid < 64) ((int*)(xT + (size_t)s * 2052 * 64))[tid] = 0;
  if (q == 3 && tid < 64) ((int*)(xT + ((size_t)s * 2052 + 2050) * 64))[tid] = 0;
}

// ---------------------------------------------------------------------------
// Kernel B (main): block = (sample, group), 512 thr / 8 waves. NO x-LDS:
// B-fragments loaded directly from xT (one dwordx4 each, all independent),
// A-fragments from Wb. Barrier only at the GN reduction.
// ---------------------------------------------------------------------------
__global__ __launch_bounds__(512, 4)
void conv_gn_direct(const short* __restrict__ xT,
                    const short* __restrict__ Wb,
                    const float* __restrict__ conv_b,
                    const float* __restrict__ gamma,
                    const float* __restrict__ beta,
                    float* __restrict__ out){
  __shared__ float redS[8], redQ[8], bc2[2];

  const int bid    = blockIdx.x;
  const int sample = ((bid & 7) << 5) + (bid >> 5);  // R2 swizzle (same XCD)
  const int g      = (bid >> 3) & 3;
  const int b      = sample >> 3;
  const int tid    = threadIdx.x;
  const int lane   = tid & 63;
  const int wid    = tid >> 6;          // 0..7
  const int l16    = lane & 15;
  const int lk     = lane >> 4;         // 0..3
  const int T0     = wid << 7;          // wave owns t in [T0, T0+128)

  f32x4 acc[2][8];
#pragma unroll
  for (int m2 = 0; m2 < 2; ++m2)
#pragma unroll
    for (int n = 0; n < 8; ++n) acc[m2][n] = (f32x4){0.f,0.f,0.f,0.f};

  const size_t wb_base = (size_t)b * 5 * 128 * 64;

#pragma unroll
  for (int ch = 0; ch < 2; ++ch) {
    // row(t,j) = 2t + j  (pad +2 folded in); per-lane base, j/nn as offsets
    const short* xbase = xT + ((size_t)sample * 2052 + 2 * (T0 + l16)) * 64
                            + ch * 32 + lk * 8;
#pragma unroll
    for (int j = 0; j < 5; ++j) {
      const short* apb = Wb + wb_base + (size_t)(j * 128 + g * 32) * 64 + ch * 32 + lk * 8;
      bf16x8 a0 = *(const bf16x8*)(apb + (size_t)l16 * 64);
      bf16x8 a1 = *(const bf16x8*)(apb + (size_t)(l16 + 16) * 64);
#pragma unroll
      for (int nn = 0; nn < 8; ++nn) {
        bf16x8 bfr = *(const bf16x8*)(xbase + nn * 2048 + j * 64);
        acc[0][nn] = __builtin_amdgcn_mfma_f32_16x16x32_bf16(a0, bfr, acc[0][nn], 0, 0, 0);
        acc[1][nn] = __builtin_amdgcn_mfma_f32_16x16x32_bf16(a1, bfr, acc[1][nn], 0, 0, 0);
      }
    }
  }

  // ---- epilogue: bias + ReLU + GroupNorm over 32co x 1024t
  float cb_[2][4], ga_[2][4], be_[2][4];
#pragma unroll
  for (int m2 = 0; m2 < 2; ++m2)
#pragma unroll
    for (int r = 0; r < 4; ++r) {
      int co = g * 32 + m2 * 16 + lk * 4 + r;
      cb_[m2][r] = conv_b[co];
      ga_[m2][r] = gamma[co];
      be_[m2][r] = beta[co];
    }
  float s1 = 0.f, s2 = 0.f;
#pragma unroll
  for (int m2 = 0; m2 < 2; ++m2)
#pragma unroll
    for (int n = 0; n < 8; ++n)
#pragma unroll
      for (int r = 0; r < 4; ++r) {
        float v = acc[m2][n][r] + cb_[m2][r];
        v = v > 0.f ? v : 0.f;
        acc[m2][n][r] = v;
        s1 += v;
        s2 = fmaf(v, v, s2);
      }
#pragma unroll
  for (int off = 32; off; off >>= 1) {
    s1 += __shfl_down(s1, off);
    s2 += __shfl_down(s2, off);
  }
  if (lane == 0) { redS[wid] = s1; redQ[wid] = s2; }
  __syncthreads();
  if (tid == 0) {
    float a = 0.f, q = 0.f;
#pragma unroll
    for (int w = 0; w < 8; ++w) { a += redS[w]; q += redQ[w]; }
    float mean = a * (1.f / 32768.f);
    float var  = q * (1.f / 32768.f) - mean * mean;
    bc2[0] = mean;
    bc2[1] = rsqrtf(var + EPSV);
  }
  __syncthreads();
  const float mean = bc2[0], inv = bc2[1];
  float* ob = out + (size_t)sample * 128 * 1024;
#pragma unroll
  for (int m2 = 0; m2 < 2; ++m2)
#pragma unroll
    for (int r = 0; r < 4; ++r) {
      int co = g * 32 + m2 * 16 + lk * 4 + r;
      float aa = ga_[m2][r] * inv;
      float bb = be_[m2][r] - mean * aa;
      float* orow = ob + (size_t)co * 1024 + T0 + l16;
#pragma unroll
      for (int n = 0; n < 8; ++n)
        orow[n * 16] = acc[m2][n][r] * aa + bb;
    }
}

// ---------------------------------------------------------------------------
// Fallback (R5 path) if ws_size is too small for xT.
// ---------------------------------------------------------------------------
#define PITCH 36
#define TILE_SH (66 * PITCH)
#define WTILE_SH (2 * TILE_SH)
__global__ __launch_bounds__(512, 4)
void conv_gn_fallback(const float* __restrict__ x,
                      const short* __restrict__ Wb,
                      const float* __restrict__ conv_b,
                      const float* __restrict__ gamma,
                      const float* __restrict__ beta,
                      float* __restrict__ out){
  __shared__ short xt[8 * WTILE_SH];
  __shared__ float redS[8], redQ[8], bc2[2];
  const int bid    = blockIdx.x;
  const int sample = ((bid & 7) << 5) + (bid >> 5);
  const int g      = (bid >> 3) & 3;
  const int b      = sample >> 3;
  const int tid    = threadIdx.x;
  const int lane   = tid & 63;
  const int wid    = tid >> 6;
  const int l16    = lane & 15;
  const int lk     = lane >> 4;
  short* xe = xt + wid * WTILE_SH;
  short* xo = xe + TILE_SH;
  f32x4 acc[2][8];
#pragma unroll
  for (int m2 = 0; m2 < 2; ++m2)
#pragma unroll
    for (int n = 0; n < 8; ++n) acc[m2][n] = (f32x4){0.f,0.f,0.f,0.f};
  const size_t wb_base = (size_t)b * 5 * 128 * 64;
  const float* xsamp = x + (size_t)sample * 64 * 2048;
#pragma unroll
  for (int ph = 0; ph < 4; ++ph) {
    const int ch = ph >> 1, th = ph & 1;
    const int T0 = th * 512 + wid * 64;
    const float* xb = xsamp + (size_t)(ch * 32) * 2048;
    const int c = 2 * T0 + 2 * (int)lane;
#pragma unroll
    for (int rg = 0; rg < 8; ++rg) {
      const float* r = xb + (size_t)(rg * 4) * 2048 + c;
      float2 v0 = *(const float2*)(r);
      float2 v1 = *(const float2*)(r + 2048);
      float2 v2 = *(const float2*)(r + 4096);
      float2 v3 = *(const float2*)(r + 6144);
      int2 ev = { pk2(v0.x, v1.x), pk2(v2.x, v3.x) };
      int2 od = { pk2(v0.y, v1.y), pk2(v2.y, v3.y) };
      *(int2*)(xe + (lane + 1) * PITCH + rg * 4) = ev;
      *(int2*)(xo + (lane + 1) * PITCH + rg * 4) = od;
    }
    if (lane < 32) {
      float2 h{0.f, 0.f};
      if (T0 > 0) h = *(const float2*)(xb + (size_t)lane * 2048 + (2 * T0 - 2));
      xe[lane] = f2bf(h.x);
      xo[lane] = f2bf(h.y);
    } else {
      const int ci = lane - 32, xc = 2 * T0 + 128;
      float v = (xc < 2048) ? xb[(size_t)ci * 2048 + xc] : 0.f;
      xe[65 * PITCH + ci] = f2bf(v);
    }
#pragma unroll
    for (int j = 0; j < 5; ++j) {
      const short* apb = Wb + wb_base + (size_t)(j * 128 + g * 32) * 64 + ch * 32 + lk * 8;
      bf16x8 a0 = *(const bf16x8*)(apb + (size_t)l16 * 64);
      bf16x8 a1 = *(const bf16x8*)(apb + (size_t)(l16 + 16) * 64);
      const short* arr = (j & 1) ? xo : xe;
      const int joff = (j & 1) ? ((j - 1) >> 1) : (j >> 1);
#pragma unroll
      for (int nn = 0; nn < 4; ++nn) {
        int tl = nn * 16 + l16;
        const short* bp = arr + (tl + joff) * PITCH + lk * 8;
        bf16x4 lo = *(const bf16x4*)bp;
        bf16x4 hi = *(const bf16x4*)(bp + 4);
        bf16x8 bfr = {lo[0],lo[1],lo[2],lo[3],hi[0],hi[1],hi[2],hi[3]};
        const int n = th * 4 + nn;
        acc[0][n] = __builtin_amdgcn_mfma_f32_16x16x32_bf16(a0, bfr, acc[0][n], 0, 0, 0);
        acc[1][n] = __builtin_amdgcn_mfma_f32_16x16x32_bf16(a1, bfr, acc[1][n], 0, 0, 0);
      }
    }
  }
  float cb_[2][4], ga_[2][4], be_[2][4];
#pragma unroll
  for (int m2 = 0; m2 < 2; ++m2)
#pragma unroll
    for (int r = 0; r < 4; ++r) {
      int co = g * 32 + m2 * 16 + lk * 4 + r;
      cb_[m2][r] = conv_b[co]; ga_[m2][r] = gamma[co]; be_[m2][r] = beta[co];
    }
  float s1 = 0.f, s2 = 0.f;
#pragma unroll
  for (int m2 = 0; m2 < 2; ++m2)
#pragma unroll
    for (int n = 0; n < 8; ++n)
#pragma unroll
      for (int r = 0; r < 4; ++r) {
        float v = acc[m2][n][r] + cb_[m2][r];
        v = v > 0.f ? v : 0.f;
        acc[m2][n][r] = v; s1 += v; s2 = fmaf(v, v, s2);
      }
#pragma unroll
  for (int off = 32; off; off >>= 1) { s1 += __shfl_down(s1, off); s2 += __shfl_down(s2, off); }
  if (lane == 0) { redS[wid] = s1; redQ[wid] = s2; }
  __syncthreads();
  if (tid == 0) {
    float a = 0.f, q = 0.f;
#pragma unroll
    for (int w = 0; w < 8; ++w) { a += redS[w]; q += redQ[w]; }
    float mean = a * (1.f / 32768.f);
    float var  = q * (1.f / 32768.f) - mean * mean;
    bc2[0] = mean; bc2[1] = rsqrtf(var + EPSV);
  }
  __syncthreads();
  const float mean = bc2[0], inv = bc2[1];
  float* ob = out + (size_t)sample * 128 * 1024;
#pragma unroll
  for (int m2 = 0; m2 < 2; ++m2)
#pragma unroll
    for (int r = 0; r < 4; ++r) {
      int co = g * 32 + m2 * 16 + lk * 4 + r;
      float aa = ga_[m2][r] * inv;
      float bb = be_[m2][r] - mean * aa;
      float* orow = ob + (size_t)co * 1024 + l16;
#pragma unroll
      for (int n = 0; n < 8; ++n) {
        int t = (n >> 2) * 512 + wid * 64 + (n & 3) * 16;
        orow[t] = acc[m2][n][r] * aa + bb;
      }
    }
}

// ---------------------------------------------------------------------------
extern "C" void kernel_launch(void* const* d_in, const int* in_sizes, int n_in,
                              void* d_out, int out_size, void* d_ws, size_t ws_size,
                              hipStream_t stream) {
  const float* x       = (const float*)d_in[0];
  const float* A_flat  = (const float*)d_in[1];
  const float* B_flat  = (const float*)d_in[2];
  const float* conv_w  = (const float*)d_in[3];
  const float* conv_b  = (const float*)d_in[4];
  const float* gamma   = (const float*)d_in[5];
  const float* beta    = (const float*)d_in[6];
  const float* scale_p = (const float*)d_in[9];

  float* out = (float*)d_out;
  short* Wb  = (short*)d_ws;                      // 2,621,440 B
  short* xT  = Wb + 32 * 5 * 128 * 64;            // 67,239,936 B
  const size_t need = 2621440ull + 67239936ull;

  build_weights<<<5120, 256, 0, stream>>>(A_flat, B_flat, conv_w, scale_p, Wb);
  if (ws_size >= need) {
    xpose<<<1024, 256, 0, stream>>>(x, xT);
    conv_gn_direct<<<1024, 512, 0, stream>>>(xT, Wb, conv_b, gamma, beta, out);
  } else {
    conv_gn_fallback<<<1024, 512, 0, stream>>>(x, Wb, conv_b, gamma, beta, out);
  }
}

// Round 7
// 112.938 us; speedup vs baseline: 1.4617x; 1.4617x over previous
//
#include <hip/hip_runtime.h>
#include <hip/hip_bf16.h>

#define EPSV 1e-5f
#define PITCH 36               // shorts per pcol (32 ci + 4 pad) = 72 B
#define PCOLS 516              // pcol 0 halo | 1..512 main | 513 halo

typedef short bf16x8 __attribute__((ext_vector_type(8)));
typedef short bf16x4 __attribute__((ext_vector_type(4)));
typedef float f32x4  __attribute__((ext_vector_type(4)));

__device__ __forceinline__ short f2bf(float f){
  unsigned u = __float_as_uint(f);
  u += 0x7fff + ((u >> 16) & 1);     // RNE
  return (short)(u >> 16);
}
__device__ __forceinline__ int pk2(float a, float b){
  __hip_bfloat162 h = __float22bfloat162_rn(float2{a, b});
  return *reinterpret_cast<int*>(&h);
}

// ---------------------------------------------------------------------------
// Kernel A: Wb[b][j][co][ci] = bf16(conv_w[co][ci][j] + scale*(B@A)[b][co][ci*5+j])
// ---------------------------------------------------------------------------
__global__ void build_weights(const float* __restrict__ A_flat,
                              const float* __restrict__ B_flat,
                              const float* __restrict__ conv_w,
                              const float* __restrict__ scale_p,
                              short* __restrict__ Wb){
  int idx = blockIdx.x * 256 + threadIdx.x;   // ((b*5+j)*128 + co)*64 + ci
  int ci = idx & 63;
  int co = (idx >> 6) & 127;
  int bj = idx >> 13;          // 0..159
  int b  = bj / 5;
  int j  = bj - 5 * b;
  int m  = ci * 5 + j;
  const float* Bp = B_flat + (b * 128 + co) * 8;
  const float* Ap = A_flat + b * 8 * 320 + m;
  float d = 0.f;
#pragma unroll
  for (int r = 0; r < 8; ++r) d = fmaf(Bp[r], Ap[r * 320], d);
  float w = conv_w[co * 320 + m] + scale_p[0] * d;
  Wb[idx] = f2bf(w);
}

// ---------------------------------------------------------------------------
// Kernel B: block = (sample, co-half). 512 thr / 8 waves, 1 blk/CU.
// 64 co per block -> each B-frag feeds 4 MFMAs. 4 phases (t-half x ci-chunk),
// double-buffered LDS; next phase's loads issued before current compute
// (T14 split). Parity-split layout (R4: measured 0 conflicts).
// ---------------------------------------------------------------------------
__global__ __launch_bounds__(512, 2)
void conv_gn_mfma(const float* __restrict__ x,
                  const short* __restrict__ Wb,
                  const float* __restrict__ conv_b,
                  const float* __restrict__ gamma,
                  const float* __restrict__ beta,
                  float* __restrict__ out){
  __shared__ short xbuf[2][2][PCOLS * PITCH];   // [buf][parity] = 148608 B
  __shared__ float redS[2][8], redQ[2][8], bcv[4];

  const int bid    = blockIdx.x;       // 512 blocks
  const int xcd    = bid & 7;
  const int u      = bid >> 3;
  const int sample = xcd * 32 + (u >> 1);   // pair blocks 8 bids apart, same XCD
  const int h      = u & 1;                 // co-half: co in [64h, 64h+64)
  const int b      = sample >> 3;
  const int tid    = threadIdx.x;
  const int lane   = tid & 63;
  const int wid    = tid >> 6;         // 0..7
  const int l16    = lane & 15;
  const int lk     = lane >> 4;        // 0..3

  f32x4 acc[4][8];
#pragma unroll
  for (int m2 = 0; m2 < 4; ++m2)
#pragma unroll
    for (int n = 0; n < 8; ++n) acc[m2][n] = (f32x4){0.f,0.f,0.f,0.f};

  const size_t wb_base = (size_t)b * 5 * 128 * 64;
  const float* xsamp = x + (size_t)sample * 64 * 2048;
  const int hwhich = tid >> 5, hci = tid & 31;     // halo role (tid<128)

  // ---- prologue: stage phase 0 (th=0, ch=0) into buf0
  {
    const float* xr = xsamp + (size_t)(wid * 4) * 2048;
    short* xe = xbuf[0][0];
    short* xo = xbuf[0][1];
#pragma unroll
    for (int pass = 0; pass < 8; ++pass) {
      int c0 = pass * 128 + lane * 2;
      float2 v0 = *(const float2*)(xr + c0);
      float2 v1 = *(const float2*)(xr + c0 + 2048);
      float2 v2 = *(const float2*)(xr + c0 + 4096);
      float2 v3 = *(const float2*)(xr + c0 + 6144);
      int2 ev = { pk2(v0.x, v1.x), pk2(v2.x, v3.x) };
      int2 od = { pk2(v0.y, v1.y), pk2(v2.y, v3.y) };
      *(int2*)(xe + (pass * 64 + lane + 1) * PITCH + wid * 4) = ev;
      *(int2*)(xo + (pass * 64 + lane + 1) * PITCH + wid * 4) = od;
    }
    if (tid < 128) {
      int xc = (hwhich < 2) ? (hwhich - 2) : (1024 + (hwhich & 1));
      float v = (xc >= 0 && xc < 2048) ? xsamp[(size_t)hci * 2048 + xc] : 0.f;
      short* arr = (hwhich & 1) ? xo : xe;
      arr[((hwhich < 2) ? 0 : 513) * PITCH + hci] = f2bf(v);
    }
  }
  __syncthreads();

#define COMPUTE_J(J, TH, CH, XE, XO)                                            \
  {                                                                             \
    const short* arr = ((J) & 1) ? (XO) : (XE);                                 \
    const int joff = ((J) & 1) ? (((J) - 1) >> 1) : ((J) >> 1);                 \
    const short* apb = Wb + wb_base + (size_t)((J) * 128 + h * 64) * 64         \
                          + (CH) * 32 + lk * 8;                                 \
    bf16x8 a0 = *(const bf16x8*)(apb + (size_t)(l16)      * 64);                \
    bf16x8 a1 = *(const bf16x8*)(apb + (size_t)(l16 + 16) * 64);                \
    bf16x8 a2 = *(const bf16x8*)(apb + (size_t)(l16 + 32) * 64);                \
    bf16x8 a3 = *(const bf16x8*)(apb + (size_t)(l16 + 48) * 64);                \
    _Pragma("unroll")                                                           \
    for (int nn = 0; nn < 4; ++nn) {                                            \
      int tl = wid * 64 + nn * 16 + l16;                                        \
      const short* bp = arr + (tl + joff) * PITCH + lk * 8;                     \
      bf16x4 lo = *(const bf16x4*)bp;                                           \
      bf16x4 hi = *(const bf16x4*)(bp + 4);                                     \
      bf16x8 bfr = {lo[0],lo[1],lo[2],lo[3],hi[0],hi[1],hi[2],hi[3]};           \
      const int n = (TH) * 4 + nn;                                              \
      acc[0][n] = __builtin_amdgcn_mfma_f32_16x16x32_bf16(a0, bfr, acc[0][n], 0,0,0); \
      acc[1][n] = __builtin_amdgcn_mfma_f32_16x16x32_bf16(a1, bfr, acc[1][n], 0,0,0); \
      acc[2][n] = __builtin_amdgcn_mfma_f32_16x16x32_bf16(a2, bfr, acc[2][n], 0,0,0); \
      acc[3][n] = __builtin_amdgcn_mfma_f32_16x16x32_bf16(a3, bfr, acc[3][n], 0,0,0); \
    }                                                                           \
  }

  float2 pf[16];
  float hv = 0.f;

#pragma unroll
  for (int ph = 0; ph < 4; ++ph) {
    const int th = ph >> 1, ch = ph & 1;
    short* xe = xbuf[ph & 1][0];
    short* xo = xbuf[ph & 1][1];
    const int nth = (ph + 1) >> 1, nch = (ph + 1) & 1;
    const float* nxb = xsamp + (size_t)(nch * 32) * 2048;
    const float* nxr = nxb + (size_t)(wid * 4) * 2048 + nth * 1024;
    short* nxe = xbuf[(ph + 1) & 1][0];
    short* nxo = xbuf[(ph + 1) & 1][1];

    // ---- issue chunk0 loads for next phase (passes 0..3) + halo
    if (ph < 3) {
#pragma unroll
      for (int pass = 0; pass < 4; ++pass) {
        int c0 = pass * 128 + lane * 2;
        pf[pass*4+0] = *(const float2*)(nxr + c0);
        pf[pass*4+1] = *(const float2*)(nxr + c0 + 2048);
        pf[pass*4+2] = *(const float2*)(nxr + c0 + 4096);
        pf[pass*4+3] = *(const float2*)(nxr + c0 + 6144);
      }
      if (tid < 128) {
        int xc = nth * 1024 + ((hwhich < 2) ? (hwhich - 2) : (1024 + (hwhich & 1)));
        hv = (xc >= 0 && xc < 2048) ? nxb[(size_t)hci * 2048 + xc] : 0.f;
      }
    }

    COMPUTE_J(0, th, ch, xe, xo)
    COMPUTE_J(1, th, ch, xe, xo)
    COMPUTE_J(2, th, ch, xe, xo)

    if (ph < 3) {
      // ---- write chunk0 into idle buffer, then issue chunk1
#pragma unroll
      for (int pass = 0; pass < 4; ++pass) {
        int2 ev = { pk2(pf[pass*4+0].x, pf[pass*4+1].x), pk2(pf[pass*4+2].x, pf[pass*4+3].x) };
        int2 od = { pk2(pf[pass*4+0].y, pf[pass*4+1].y), pk2(pf[pass*4+2].y, pf[pass*4+3].y) };
        *(int2*)(nxe + (pass * 64 + lane + 1) * PITCH + wid * 4) = ev;
        *(int2*)(nxo + (pass * 64 + lane + 1) * PITCH + wid * 4) = od;
      }
      if (tid < 128) {
        short* arr = (hwhich & 1) ? nxo : nxe;
        arr[((hwhich < 2) ? 0 : 513) * PITCH + hci] = f2bf(hv);
      }
#pragma unroll
      for (int pass = 4; pass < 8; ++pass) {
        int c0 = pass * 128 + lane * 2;
        pf[(pass-4)*4+0] = *(const float2*)(nxr + c0);
        pf[(pass-4)*4+1] = *(const float2*)(nxr + c0 + 2048);
        pf[(pass-4)*4+2] = *(const float2*)(nxr + c0 + 4096);
        pf[(pass-4)*4+3] = *(const float2*)(nxr + c0 + 6144);
      }
    }

    COMPUTE_J(3, th, ch, xe, xo)
    COMPUTE_J(4, th, ch, xe, xo)

    if (ph < 3) {
#pragma unroll
      for (int pass = 4; pass < 8; ++pass) {
        int2 ev = { pk2(pf[(pass-4)*4+0].x, pf[(pass-4)*4+1].x), pk2(pf[(pass-4)*4+2].x, pf[(pass-4)*4+3].x) };
        int2 od = { pk2(pf[(pass-4)*4+0].y, pf[(pass-4)*4+1].y), pk2(pf[(pass-4)*4+2].y, pf[(pass-4)*4+3].y) };
        *(int2*)(nxe + (pass * 64 + lane + 1) * PITCH + wid * 4) = ev;
        *(int2*)(nxo + (pass * 64 + lane + 1) * PITCH + wid * 4) = od;
      }
    }
    __syncthreads();
  }

  // ---- epilogue: bias + ReLU + two-group GroupNorm (co halves of the 64)
  float cb_[4][4], ga_[4][4], be_[4][4];
#pragma unroll
  for (int m2 = 0; m2 < 4; ++m2)
#pragma unroll
    for (int r = 0; r < 4; ++r) {
      int co = h * 64 + m2 * 16 + lk * 4 + r;
      cb_[m2][r] = conv_b[co];
      ga_[m2][r] = gamma[co];
      be_[m2][r] = beta[co];
    }
  float s1[2] = {0.f, 0.f}, s2[2] = {0.f, 0.f};
#pragma unroll
  for (int m2 = 0; m2 < 4; ++m2) {
    const int grp = m2 >> 1;
#pragma unroll
    for (int n = 0; n < 8; ++n)
#pragma unroll
      for (int r = 0; r < 4; ++r) {
        float v = acc[m2][n][r] + cb_[m2][r];
        v = v > 0.f ? v : 0.f;
        acc[m2][n][r] = v;
        s1[grp] += v;
        s2[grp] = fmaf(v, v, s2[grp]);
      }
  }
#pragma unroll
  for (int off = 32; off; off >>= 1) {
    s1[0] += __shfl_down(s1[0], off);
    s2[0] += __shfl_down(s2[0], off);
    s1[1] += __shfl_down(s1[1], off);
    s2[1] += __shfl_down(s2[1], off);
  }
  if (lane == 0) {
    redS[0][wid] = s1[0]; redQ[0][wid] = s2[0];
    redS[1][wid] = s1[1]; redQ[1][wid] = s2[1];
  }
  __syncthreads();
  if (tid < 2) {
    float a = 0.f, q = 0.f;
#pragma unroll
    for (int w = 0; w < 8; ++w) { a += redS[tid][w]; q += redQ[tid][w]; }
    float mean = a * (1.f / 32768.f);
    float var  = q * (1.f / 32768.f) - mean * mean;
    bcv[tid * 2]     = mean;
    bcv[tid * 2 + 1] = rsqrtf(var + EPSV);
  }
  __syncthreads();
  float* ob = out + (size_t)sample * 128 * 1024;
#pragma unroll
  for (int m2 = 0; m2 < 4; ++m2) {
    const float mean = bcv[(m2 >> 1) * 2];
    const float inv  = bcv[(m2 >> 1) * 2 + 1];
#pragma unroll
    for (int r = 0; r < 4; ++r) {
      int co = h * 64 + m2 * 16 + lk * 4 + r;
      float aa = ga_[m2][r] * inv;
      float bb = be_[m2][r] - mean * aa;
      float* orow = ob + (size_t)co * 1024 + l16;
#pragma unroll
      for (int n = 0; n < 8; ++n) {
        int t = (n >> 2) * 512 + wid * 64 + (n & 3) * 16;
        orow[t] = acc[m2][n][r] * aa + bb;
      }
    }
  }
}

// ---------------------------------------------------------------------------
extern "C" void kernel_launch(void* const* d_in, const int* in_sizes, int n_in,
                              void* d_out, int out_size, void* d_ws, size_t ws_size,
                              hipStream_t stream) {
  const float* x       = (const float*)d_in[0];
  const float* A_flat  = (const float*)d_in[1];
  const float* B_flat  = (const float*)d_in[2];
  const float* conv_w  = (const float*)d_in[3];
  const float* conv_b  = (const float*)d_in[4];
  const float* gamma   = (const float*)d_in[5];
  const float* beta    = (const float*)d_in[6];
  const float* scale_p = (const float*)d_in[9];

  float* out = (float*)d_out;
  short* Wb  = (short*)d_ws;   // 32*5*128*64 bf16 = 2.62 MB

  build_weights<<<5120, 256, 0, stream>>>(A_flat, B_flat, conv_w, scale_p, Wb);
  conv_gn_mfma<<<512, 512, 0, stream>>>(x, Wb, conv_b, gamma, beta, out);
}